// Round 3
// baseline (233.661 us; speedup 1.0000x reference)
//
#include <hip/hip_runtime.h>
#include <cmath>
#include <complex>

// Problem constants
constexpr int TT  = 50;            // time length
constexpr int NB  = 50;            // batch
constexpr int NC  = 4096;          // channels
constexpr int NCH = NB * NC;       // 204800 independent series
constexpr int PAD = 49;
constexpr int EXT = TT + 2 * PAD;  // 148
constexpr int CT  = 16;            // channel tile per block (block = CT x NB threads)
constexpr int PF  = 5;             // x prefetch depth (divides TT)
constexpr int TH  = TT / 2;        // 25 float2 accumulators per band

// Per-band stats + publish, statically bound (NO runtime-indexed register arrays --
// rule: dynamic indexing of register arrays goes to scratch). References resolve at
// compile time. Accumulation order over t is ascending (x then y), identical to the
// verified scalar kernel -> bit-identical f32.
__device__ __forceinline__ void stats_publish(const float2 (&f)[TH],
                                              float (*sm_mu)[CT], float (*sm_inv)[CT],
                                              int b, int tx) {
    float mu = 0.f;
#pragma unroll
    for (int t2 = 0; t2 < TH; ++t2) { mu += f[t2].x; mu += f[t2].y; }
    mu *= (1.0f / TT);
    float ss = 0.f;
#pragma unroll
    for (int t2 = 0; t2 < TH; ++t2) {
        const float hx = f[t2].x - mu;
        ss = fmaf(hx, hx, ss);
        const float hy = f[t2].y - mu;
        ss = fmaf(hy, hy, ss);
    }
    const float inv = 1.0f / sqrtf(ss * (1.0f / (TT - 1)));
    sm_mu [b][tx] = mu;
    sm_inv[b][tx] = inv;
}

// ---------------- Main kernel -------------------------------------------------------
// Block = (CT channels) x (all 50 batches). Thread (c,b) computes, FOR BOTH BANDS IN
// ONE PASS, y[.,b,c] = M_band x[.,b,c] in float2 register accumulators. Band fusion
// halves the global x loads (each column read exactly once) and gives every PF=5
// prefetch group 500 FMAs of latency cover -> HBM miss latency hidden at ~3 waves/SIMD.
// float2 accumulators pair the INDEPENDENT per-t chains so the SLP vectorizer can emit
// v_pk_fma_f32 (2x f32/inst, halves k-loop VALU); per-chain op order is unchanged ->
// bit-identical to the verified scalar kernel (scalar fallback = old code exactly).
// Stats go to LDS (one barrier), then the REFERENCE'S BROADCASTING QUIRK is applied:
// out[t,b,c] = (y[t,b,c] - mu[t,c]) * invs[t,c] -- stats indexed by the TIME position
// t (batch row t), not by b. That quirk is why ref absmax ~ 2960.
__global__ void __launch_bounds__(CT * NB)
filt_main(const float* __restrict__ x, const float* __restrict__ Mt,
          float* __restrict__ out) {
    const int tx = threadIdx.x;                 // channel within tile
    const int b  = threadIdx.y;                 // batch
    const int c  = blockIdx.x * CT + tx;
    const int i  = b * NC + c;                  // channel index into [B,C] plane

    __shared__ float sm_mu [2][NB][CT];
    __shared__ float sm_inv[2][NB][CT];

    const float* __restrict__ xcol = x + i;
    const float* __restrict__ M0 = Mt;              // rows are 200 B -> float2-aligned
    const float* __restrict__ M1 = Mt + TT * TT;

    float2 f0[TH], f1[TH];
#pragma unroll
    for (int t2 = 0; t2 < TH; ++t2) {
        f0[t2] = make_float2(0.f, 0.f);
        f1[t2] = make_float2(0.f, 0.f);
    }

    // prime the prefetch pipeline
    float xa[PF];
#pragma unroll
    for (int p = 0; p < PF; ++p) xa[p] = xcol[(size_t)p * NCH];

#pragma unroll 1                                // keep body small (I$), rely on prefetch
    for (int kb = 0; kb < TT; kb += PF) {
        // issue next group's loads NOW; consumed only in the next iteration.
        // clamp (branchless): last iter harmlessly re-reads slice 0 (cache-hot).
        const int kn = (kb + PF < TT) ? (kb + PF) : 0;
        float xn[PF];
#pragma unroll
        for (int p = 0; p < PF; ++p) xn[p] = xcol[(size_t)(kn + p) * NCH];

#pragma unroll
        for (int p = 0; p < PF; ++p) {
            const float xk = xa[p];
            // finish band 0's row before touching band 1's (limits live SGPR window)
            const float2* __restrict__ r0 =
                reinterpret_cast<const float2*>(M0 + (kb + p) * TT);  // uniform -> s_load
#pragma unroll
            for (int t2 = 0; t2 < TH; ++t2) {
                f0[t2].x = fmaf(r0[t2].x, xk, f0[t2].x);
                f0[t2].y = fmaf(r0[t2].y, xk, f0[t2].y);
            }
            const float2* __restrict__ r1 =
                reinterpret_cast<const float2*>(M1 + (kb + p) * TT);
#pragma unroll
            for (int t2 = 0; t2 < TH; ++t2) {
                f1[t2].x = fmaf(r1[t2].x, xk, f1[t2].x);
                f1[t2].y = fmaf(r1[t2].y, xk, f1[t2].y);
            }
        }
#pragma unroll
        for (int p = 0; p < PF; ++p) xa[p] = xn[p];             // rotate (SSA-renamed)
    }

    // per-(b,c) stats (ddof=1 std about the actual mean, matching np.std)
    stats_publish(f0, sm_mu[0], sm_inv[0], b, tx);
    stats_publish(f1, sm_mu[1], sm_inv[1], b, tx);
    __syncthreads();   // single barrier: both bands' stats published

#pragma unroll
    for (int t2 = 0; t2 < TH; ++t2) {
        const int t = 2 * t2;
        const float vx = (f0[t2].x - sm_mu[0][t][tx]) * sm_inv[0][t][tx];       // QUIRK: [t]
        __builtin_nontemporal_store(vx, out + (size_t)t * NCH + i);
        const float vy = (f0[t2].y - sm_mu[0][t + 1][tx]) * sm_inv[0][t + 1][tx];
        __builtin_nontemporal_store(vy, out + (size_t)(t + 1) * NCH + i);
    }
#pragma unroll
    for (int t2 = 0; t2 < TH; ++t2) {
        const int t = 2 * t2;
        const float vx = (f1[t2].x - sm_mu[1][t][tx]) * sm_inv[1][t][tx];       // QUIRK: [t]
        __builtin_nontemporal_store(vx, out + (size_t)(TT + t) * NCH + i);
        const float vy = (f1[t2].y - sm_mu[1][t + 1][tx]) * sm_inv[1][t + 1][tx];
        __builtin_nontemporal_store(vy, out + (size_t)(TT + t + 1) * NCH + i);
    }
}

// ---------------- Host: Butterworth bandpass SOS + zi (reference-exact, double) ----
struct Coefs {
    double b0[2][2], b1[2][2], b2[2][2], a1[2][2], a2[2][2];
    double zi0[2][2], zi1[2][2];
};

static Coefs make_coefs() {
    Coefs cf;
    const double bands[2][2] = {{0.05, 0.15}, {0.2, 0.4}};
    const int n = 2;  // ORDER
    for (int bd = 0; bd < 2; ++bd) {
        const double fs = 2.0;
        const double w1 = bands[bd][0], w2 = bands[bd][1];
        const double warped0 = 2.0 * fs * std::tan(M_PI * w1 / fs);
        const double warped1 = 2.0 * fs * std::tan(M_PI * w2 / fs);
        const double bw = warped1 - warped0;
        const double wo = std::sqrt(warped0 * warped1);
        std::complex<double> p_bp[4];
        for (int k = 1; k <= n; ++k) {
            std::complex<double> p = -std::exp(std::complex<double>(0.0, M_PI * (2 * k - 1) / (2.0 * n)));
            std::complex<double> plp = p * (bw / 2.0);
            std::complex<double> disc = std::sqrt(plp * plp - std::complex<double>(wo * wo, 0.0));
            p_bp[k - 1] = plp + disc;
            p_bp[n + k - 1] = plp - disc;
        }
        const double fs2 = 2.0 * fs;
        std::complex<double> prod(1.0, 0.0);
        for (int i = 0; i < 2 * n; ++i) prod *= (fs2 - p_bp[i]);
        const double gain = std::pow(bw, n) * std::pow(fs2, n) / prod.real();
        std::complex<double> p_d[4];
        for (int i = 0; i < 2 * n; ++i) p_d[i] = (fs2 + p_bp[i]) / (fs2 - p_bp[i]);
        double sos[2][6];
        int cnt = 0;
        for (int i = 0; i < 2 * n; ++i) {
            if (p_d[i].imag() > 0) {
                const double g = (cnt == 0) ? gain : 1.0;
                sos[cnt][0] = g;
                sos[cnt][1] = 0.0;
                sos[cnt][2] = -g;
                sos[cnt][3] = 1.0;
                sos[cnt][4] = -2.0 * p_d[i].real();
                sos[cnt][5] = std::norm(p_d[i]);
                ++cnt;
            }
        }
        double scale = 1.0;
        for (int s = 0; s < 2; ++s) {
            const double b0 = sos[s][0], b1 = sos[s][1], b2 = sos[s][2];
            const double a1 = sos[s][4], a2 = sos[s][5];
            const double B0 = b1 - a1 * b0, B1 = b2 - a2 * b0;
            const double det = 1.0 + a1 + a2;
            cf.b0[bd][s] = b0; cf.b1[bd][s] = b1; cf.b2[bd][s] = b2;
            cf.a1[bd][s] = a1; cf.a2[bd][s] = a2;
            cf.zi0[bd][s] = scale * (B0 + B1) / det;
            cf.zi1[bd][s] = scale * ((1.0 + a1) * B1 - a2 * B0) / det;
            scale *= (b0 + b1 + b2) / (1.0 + a1 + a2);
        }
    }
    return cf;
}

// ---------------- Host: build the 2x50x50 filtfilt+demean matrix ------------------
// Mt[(band*TT + k)*TT + t] = d y[t] / d x[k] (y demeaned over t). Same double math,
// same op order as the original on-device build_M kernel -- bit-equivalent (mod FMA
// contraction differences, <=1 ulp double, invisible after f32 cast). Input-independent,
// so it's built once and hipMemcpyAsync'd (20 KB) into d_ws each launch (graph-safe:
// static host buffer, async copy on the capture stream).
struct MHost {
    float M[2 * TT * TT];
    MHost() {
        const Coefs cf = make_coefs();
        for (int band = 0; band < 2; ++band) {
            for (int j = 0; j < TT; ++j) {
                double e[EXT];
                // odd extension of basis vector e_j
                for (int i = 0; i < PAD; ++i)
                    e[i] = 2.0 * (j == 0 ? 1.0 : 0.0) - ((PAD - i) == j ? 1.0 : 0.0);
                for (int t = 0; t < TT; ++t) e[PAD + t] = (t == j) ? 1.0 : 0.0;
                for (int i = 0; i < PAD; ++i)
                    e[PAD + TT + i] = 2.0 * (j == TT - 1 ? 1.0 : 0.0) - ((TT - 2 - i) == j ? 1.0 : 0.0);

                const double x0 = e[0];
                for (int s = 0; s < 2; ++s) {
                    const double b0 = cf.b0[band][s], b1 = cf.b1[band][s], b2 = cf.b2[band][s];
                    const double a1 = cf.a1[band][s], a2 = cf.a2[band][s];
                    double z0 = cf.zi0[band][s] * x0, z1 = cf.zi1[band][s] * x0;
                    for (int i = 0; i < EXT; ++i) {
                        const double xt = e[i];
                        const double yt = b0 * xt + z0;
                        z0 = b1 * xt + z1 - a1 * yt;
                        z1 = b2 * xt - a2 * yt;
                        e[i] = yt;
                    }
                }
                const double y0 = e[EXT - 1];
                for (int s = 0; s < 2; ++s) {
                    const double b0 = cf.b0[band][s], b1 = cf.b1[band][s], b2 = cf.b2[band][s];
                    const double a1 = cf.a1[band][s], a2 = cf.a2[band][s];
                    double z0 = cf.zi0[band][s] * y0, z1 = cf.zi1[band][s] * y0;
                    for (int m = 0; m < EXT; ++m) {
                        const int i = EXT - 1 - m;
                        const double xt = e[i];
                        const double yt = b0 * xt + z0;
                        z0 = b1 * xt + z1 - a1 * yt;
                        z1 = b2 * xt - a2 * yt;
                        e[i] = yt;
                    }
                }
                // slice [PAD, PAD+TT) and fold the demean over t
                double mean = 0.0;
                for (int t = 0; t < TT; ++t) mean += e[PAD + t];
                mean *= (1.0 / TT);
                for (int t = 0; t < TT; ++t)
                    M[(band * TT + j) * TT + t] = (float)(e[PAD + t] - mean);
            }
        }
    }
};

extern "C" void kernel_launch(void* const* d_in, const int* in_sizes, int n_in,
                              void* d_out, int out_size, void* d_ws, size_t ws_size,
                              hipStream_t stream) {
    static const MHost mh;   // built once on first call; persists for graph replays
    const float* x = (const float*)d_in[0];
    float* out = (float*)d_out;
    float* Mt = (float*)d_ws;  // 2*50*50 floats = 20 KB

    hipMemcpyAsync(Mt, mh.M, sizeof(mh.M), hipMemcpyHostToDevice, stream);
    filt_main<<<dim3(NC / CT), dim3(CT, NB), 0, stream>>>(x, Mt, out);
}